// Round 1
// baseline (1270.701 us; speedup 1.0000x reference)
//
#include <hip/hip_runtime.h>
#include <math.h>

#define BB 4
#define CC 256
#define HT 32
#define WT 32
#define HH 64
#define WW 64
#define HW 4096
#define CCOMB 512

// ---------------- K1: bilinear 2x upsample (jax.image.resize half-pixel) ----------------
__global__ void upsample_kernel(const float* __restrict__ tmpl, float* __restrict__ aligned) {
    int idx = blockIdx.x * blockDim.x + threadIdx.x; // over B*C*H*W
    if (idx >= BB * CC * HW) return;
    int x = idx & 63;
    int y = (idx >> 6) & 63;
    int bc = idx >> 12;
    const float* tp = tmpl + bc * (HT * WT);
    float sy = 0.5f * (float)y - 0.25f;
    float sx = 0.5f * (float)x - 0.25f;
    float fy0 = floorf(sy), fx0 = floorf(sx);
    float wy = sy - fy0, wx = sx - fx0;
    int y0 = (int)fy0, x0 = (int)fx0;
    int y0c = min(max(y0, 0), HT - 1), y1c = min(max(y0 + 1, 0), HT - 1);
    int x0c = min(max(x0, 0), WT - 1), x1c = min(max(x0 + 1, 0), WT - 1);
    float v00 = tp[y0c * WT + x0c], v01 = tp[y0c * WT + x1c];
    float v10 = tp[y1c * WT + x0c], v11 = tp[y1c * WT + x1c];
    aligned[idx] = (1.f - wy) * ((1.f - wx) * v00 + wx * v01) +
                   wy * ((1.f - wx) * v10 + wx * v11);
}

// ---------------- K2: transpose deform weights (o,c,k) -> (k,c,o) ----------------
__global__ void transpose_w_kernel(const float* __restrict__ dw, float* __restrict__ wt) {
    int idx = blockIdx.x * blockDim.x + threadIdx.x; // 9*256*256
    if (idx >= 9 * CC * CC) return;
    int o = idx & 255;
    int c = (idx >> 8) & 255;
    int k = idx >> 16;
    wt[idx] = dw[(o * CC + c) * 9 + k];
}

// ---------------- K3: offset conv (3x3, 512->18) + mask conv (1x1, 512->9) + sigmoid ----
// block = (b, y): 512 threads = 8 waves, wave w handles channels [w*64, w*64+64)
__global__ __launch_bounds__(512) void offmask_kernel(
    const float* __restrict__ aligned, const float* __restrict__ search,
    const float* __restrict__ ow, const float* __restrict__ ob,
    const float* __restrict__ mw, const float* __restrict__ mb,
    float* __restrict__ offs, float* __restrict__ maskv) {
    int blk = blockIdx.x;       // b*64 + y
    int b = blk >> 6, y = blk & 63;
    int tid = threadIdx.x;
    int wave = tid >> 6, lane = tid & 63;  // lane == x

    float acc[27];
#pragma unroll
    for (int j = 0; j < 27; j++) acc[j] = 0.f;

    int c0 = wave * 64;
#pragma unroll 2
    for (int ci = 0; ci < 64; ci++) {
        int c = c0 + ci;
        const float* plane = (c < CC) ? (aligned + ((size_t)(b * CC + c) * HW))
                                      : (search + ((size_t)(b * CC + (c - CC)) * HW));
#pragma unroll
        for (int dy = 0; dy < 3; dy++) {
            int yy = y + dy - 1;
            float v = (yy >= 0 && yy < HH) ? plane[yy * WW + lane] : 0.f;
            float vm1 = __shfl_up(v, 1);
            if (lane == 0) vm1 = 0.f;
            float vp1 = __shfl_down(v, 1);
            if (lane == 63) vp1 = 0.f;
            const float* wrow = ow + (size_t)(c * 3 + dy) * 3;  // + oc*512*9
#pragma unroll
            for (int oc = 0; oc < 18; oc++) {
                const float* wp = wrow + (size_t)oc * CCOMB * 9;
                acc[oc] += vm1 * wp[0] + v * wp[1] + vp1 * wp[2];
            }
            if (dy == 1) {
#pragma unroll
                for (int mc = 0; mc < 9; mc++) acc[18 + mc] += v * mw[mc * CCOMB + c];
            }
        }
    }

    __shared__ float red[8 * 64 * 27];  // 55 KB
#pragma unroll
    for (int j = 0; j < 27; j++) red[(wave * 64 + lane) * 27 + j] = acc[j];
    __syncthreads();

    for (int idx = tid; idx < 64 * 27; idx += 512) {
        int x = idx / 27, j = idx % 27;
        float s = 0.f;
#pragma unroll
        for (int w_ = 0; w_ < 8; w_++) s += red[(w_ * 64 + x) * 27 + j];
        if (j < 18) {
            offs[((size_t)(b * 18 + j)) * HW + y * WW + x] = s + ob[j];
        } else {
            float m = s + mb[j - 18];
            maskv[((size_t)(b * 9 + (j - 18))) * HW + y * WW + x] = 1.f / (1.f + expf(-m));
        }
    }
}

// ---------------- K4: deformable conv gather + einsum ----------------
// block = (b, 32-pixel tile). 256 threads.
// phase0: compute bilinear params for 9 taps x 32 pixels
// phase1 (per k): gather sampled[c][t] into LDS (256 x 32)
// phase2 (per k): acc[o][t] += Wt[k][c][o] * sampled[c][t]
__global__ __launch_bounds__(256) void deform_kernel(
    const float* __restrict__ search, const float* __restrict__ offs,
    const float* __restrict__ maskv, const float* __restrict__ wt,
    const float* __restrict__ db, float* __restrict__ out) {
    int blk = blockIdx.x;  // b*128 + tile
    int b = blk >> 7, tile = blk & 127;
    int p0 = tile * 32;
    int tid = threadIdx.x;

    __shared__ int4 idxs[288];    // (k,t): 4 clamped corner flat indices
    __shared__ float4 wgts[288];  // (k,t): 4 corner weights (valid & mask folded)
    __shared__ float smp[CC * 32];

    for (int i = tid; i < 288; i += 256) {
        int k = i >> 5, t = i & 31;
        int p = p0 + t;
        int y = p >> 6, x = p & 63;
        float dy = offs[((size_t)(b * 18 + 2 * k)) * HW + p];
        float dx = offs[((size_t)(b * 18 + 2 * k + 1)) * HW + p];
        float m = maskv[((size_t)(b * 9 + k)) * HW + p];
        float py = (float)(y + k / 3 - 1) + dy;
        float px = (float)(x + k % 3 - 1) + dx;
        float fy0 = floorf(py), fx0 = floorf(px);
        float wy = py - fy0, wx = px - fx0;
        int y0 = (int)fy0, x0 = (int)fx0;
        bool vy0 = (y0 >= 0) && (y0 < HH);
        bool vy1 = (y0 + 1 >= 0) && (y0 + 1 < HH);
        bool vx0 = (x0 >= 0) && (x0 < WW);
        bool vx1 = (x0 + 1 >= 0) && (x0 + 1 < WW);
        float w00 = (vy0 && vx0) ? (1.f - wy) * (1.f - wx) * m : 0.f;
        float w01 = (vy0 && vx1) ? (1.f - wy) * wx * m : 0.f;
        float w10 = (vy1 && vx0) ? wy * (1.f - wx) * m : 0.f;
        float w11 = (vy1 && vx1) ? wy * wx * m : 0.f;
        int y0c = min(max(y0, 0), HH - 1), y1c = min(max(y0 + 1, 0), HH - 1);
        int x0c = min(max(x0, 0), WW - 1), x1c = min(max(x0 + 1, 0), WW - 1);
        idxs[i] = make_int4(y0c * WW + x0c, y0c * WW + x1c, y1c * WW + x0c, y1c * WW + x1c);
        wgts[i] = make_float4(w00, w01, w10, w11);
    }
    __syncthreads();

    float4 acc[4][2];
#pragma unroll
    for (int u = 0; u < 4; u++) {
        acc[u][0] = make_float4(0.f, 0.f, 0.f, 0.f);
        acc[u][1] = make_float4(0.f, 0.f, 0.f, 0.f);
    }

    int t_ = tid & 31, cg = tid >> 5;     // phase-1 role
    int o_lane = tid >> 2, tq = tid & 3;  // phase-2 role
    const float* sb = search + (size_t)b * CC * HW;

    for (int k = 0; k < 9; k++) {
        __syncthreads();  // smp safe to overwrite
        int4 id = idxs[k * 32 + t_];
        float4 wg = wgts[k * 32 + t_];
#pragma unroll 4
        for (int j = 0; j < 32; j++) {
            int c = cg + 8 * j;
            const float* pl = sb + (size_t)c * HW;
            float v = wg.x * pl[id.x] + wg.y * pl[id.y] + wg.z * pl[id.z] + wg.w * pl[id.w];
            smp[c * 32 + t_] = v;
        }
        __syncthreads();

        const float* wk = wt + (size_t)k * CC * 256;
#pragma unroll 4
        for (int c = 0; c < CC; c++) {
            float4 s4a = *(const float4*)&smp[c * 32 + tq * 4];
            float4 s4b = *(const float4*)&smp[c * 32 + 16 + tq * 4];
            const float* wc = wk + c * 256;
#pragma unroll
            for (int u = 0; u < 4; u++) {
                float w_ = wc[u * 64 + o_lane];
                acc[u][0].x += w_ * s4a.x;
                acc[u][0].y += w_ * s4a.y;
                acc[u][0].z += w_ * s4a.z;
                acc[u][0].w += w_ * s4a.w;
                acc[u][1].x += w_ * s4b.x;
                acc[u][1].y += w_ * s4b.y;
                acc[u][1].z += w_ * s4b.z;
                acc[u][1].w += w_ * s4b.w;
            }
        }
    }

#pragma unroll
    for (int u = 0; u < 4; u++) {
        int o = u * 64 + o_lane;
        float bias = db[o];
        float* op = out + ((size_t)(b * CC + o)) * HW + p0 + tq * 4;
        float4 r0 = make_float4(acc[u][0].x + bias, acc[u][0].y + bias,
                                acc[u][0].z + bias, acc[u][0].w + bias);
        float4 r1 = make_float4(acc[u][1].x + bias, acc[u][1].y + bias,
                                acc[u][1].z + bias, acc[u][1].w + bias);
        *(float4*)(op) = r0;
        *(float4*)(op + 16) = r1;
    }
}

extern "C" void kernel_launch(void* const* d_in, const int* in_sizes, int n_in,
                              void* d_out, int out_size, void* d_ws, size_t ws_size,
                              hipStream_t stream) {
    const float* tmpl = (const float*)d_in[0];
    const float* search = (const float*)d_in[1];
    const float* ow = (const float*)d_in[2];
    const float* ob = (const float*)d_in[3];
    const float* mw = (const float*)d_in[4];
    const float* mb = (const float*)d_in[5];
    const float* dw = (const float*)d_in[6];
    const float* db = (const float*)d_in[7];
    float* out = (float*)d_out;

    float* ws = (float*)d_ws;
    float* aligned = ws;                    // 4*256*64*64      = 4194304
    float* offsv = aligned + 4194304;       // 4*18*4096        = 294912
    float* maskv = offsv + 294912;          // 4*9*4096         = 147456
    float* wtb = maskv + 147456;            // 9*256*256        = 589824
    // total ~20.9 MB of workspace

    upsample_kernel<<<(BB * CC * HW) / 256, 256, 0, stream>>>(tmpl, aligned);
    transpose_w_kernel<<<(9 * CC * CC) / 256, 256, 0, stream>>>(dw, wtb);
    offmask_kernel<<<BB * HH, 512, 0, stream>>>(aligned, search, ow, ob, mw, mb, offsv, maskv);
    deform_kernel<<<BB * 128, 256, 0, stream>>>(search, offsv, maskv, wtb, db, out);
}

// Round 2
// 442.253 us; speedup vs baseline: 2.8732x; 2.8732x over previous
//
#include <hip/hip_runtime.h>
#include <math.h>

#define BB 4
#define CC 256
#define HT 32
#define WT 32
#define HH 64
#define WW 64
#define HW 4096
#define CCOMB 512

// ---------------- K1: transpose deform weights (o,c,k) -> (k,c,o) ----------------
__global__ void transpose_w_kernel(const float* __restrict__ dw, float* __restrict__ wt) {
    int idx = blockIdx.x * blockDim.x + threadIdx.x; // 9*256*256
    if (idx >= 9 * CC * CC) return;
    int o = idx & 255;
    int c = (idx >> 8) & 255;
    int k = idx >> 16;
    wt[idx] = dw[(o * CC + c) * 9 + k];
}

// ---------------- K2: build offset/mask weight matrix wt2[c][tap][32] ----------------
// oc 0..17 = offset conv 3x3 weights; oc 18..26 = mask 1x1 (center tap only); 27..31 = 0
__global__ void build_wt2_kernel(const float* __restrict__ ow, const float* __restrict__ mw,
                                 float* __restrict__ wt2) {
    int idx = blockIdx.x * blockDim.x + threadIdx.x; // 512*9*32
    if (idx >= CCOMB * 9 * 32) return;
    int oc = idx & 31;
    int tap = (idx >> 5) % 9;
    int c = idx / 288;
    float v = 0.f;
    if (oc < 18) v = ow[(size_t)(oc * CCOMB + c) * 9 + tap];
    else if (oc < 27 && tap == 4) v = mw[(size_t)(oc - 18) * CCOMB + c];
    wt2[idx] = v;
}

// ---------------- K3: offset+mask conv as register-tiled GEMM ----------------
// grid 512 = ks(4 K-splits of 128 c) x b(4) x ytile(32 of 2 rows). 512 threads.
// thread = (ocg 0..7, x 0..63); tile = 4 oc x 2 rows. Upsample folded into staging.
__global__ __launch_bounds__(512) void offmask_gemm(
    const float* __restrict__ tmpl, const float* __restrict__ search,
    const float* __restrict__ wt2, float* __restrict__ partial) {
    int blk = blockIdx.x;
    int ks = blk >> 7;
    int b = (blk >> 5) & 3;
    int yt = blk & 31;
    int y0 = yt * 2;
    int tid = threadIdx.x;
    int ocg = tid >> 6;
    int x = tid & 63;

    __shared__ __align__(16) float act_s[16 * 4 * 68];  // [cw][row][68], col -1..64 at idx 0..65
    __shared__ __align__(16) float wt_s[16 * 288];      // [cw][tap][32]

    float acc[4][2];
#pragma unroll
    for (int u = 0; u < 4; u++) { acc[u][0] = 0.f; acc[u][1] = 0.f; }

    int c0g = ks * 128;
    const float* tp_b = tmpl + (size_t)b * CC * (HT * WT);
    const float* se_b = search + (size_t)b * CC * HW;

    for (int chunk = 0; chunk < 8; ++chunk) {
        int cbase = c0g + chunk * 16;
        __syncthreads();
        // stage weights (coalesced contiguous copy)
        const float* wsrc = wt2 + (size_t)cbase * 288;
        for (int j = tid; j < 16 * 288; j += 512) wt_s[j] = wsrc[j];
        // stage activations (rows y0-1 .. y0+2), upsample-on-the-fly for c<256
        for (int j = tid; j < 4096; j += 512) {
            int cw = j >> 8;
            int row = (j >> 6) & 3;
            int xx = j & 63;
            int gy = y0 - 1 + row;
            float v = 0.f;
            if (gy >= 0 && gy < HH) {
                int cg = cbase + cw;
                if (cg < CC) {
                    const float* tp = tp_b + (size_t)cg * (HT * WT);
                    float sy = 0.5f * (float)gy - 0.25f;
                    float sx = 0.5f * (float)xx - 0.25f;
                    float fy0 = floorf(sy), fx0 = floorf(sx);
                    float wy = sy - fy0, wx = sx - fx0;
                    int yy0 = (int)fy0, xx0 = (int)fx0;
                    int y0c = min(max(yy0, 0), HT - 1), y1c = min(max(yy0 + 1, 0), HT - 1);
                    int x0c = min(max(xx0, 0), WT - 1), x1c = min(max(xx0 + 1, 0), WT - 1);
                    float v00 = tp[y0c * WT + x0c], v01 = tp[y0c * WT + x1c];
                    float v10 = tp[y1c * WT + x0c], v11 = tp[y1c * WT + x1c];
                    v = (1.f - wy) * ((1.f - wx) * v00 + wx * v01) +
                        wy * ((1.f - wx) * v10 + wx * v11);
                } else {
                    v = se_b[(size_t)(cg - CC) * HW + gy * WW + xx];
                }
            }
            act_s[cw * 272 + row * 68 + xx + 1] = v;
        }
        if (tid < 64) {
            int cw = tid >> 2, row = tid & 3;
            act_s[cw * 272 + row * 68 + 0] = 0.f;
            act_s[cw * 272 + row * 68 + 65] = 0.f;
        }
        __syncthreads();

#pragma unroll 2
        for (int cw = 0; cw < 16; ++cw) {
            float a[4][3];
#pragma unroll
            for (int row = 0; row < 4; ++row)
#pragma unroll
                for (int kx = 0; kx < 3; ++kx)
                    a[row][kx] = act_s[cw * 272 + row * 68 + x + kx];
            const float* wp = &wt_s[cw * 288 + ocg * 4];
#pragma unroll
            for (int t = 0; t < 9; ++t) {
                float4 w4 = *(const float4*)(wp + t * 32);
                int ky = t / 3, kx = t % 3;
#pragma unroll
                for (int r = 0; r < 2; ++r) {
                    float av = a[r + ky][kx];
                    acc[0][r] += w4.x * av;
                    acc[1][r] += w4.y * av;
                    acc[2][r] += w4.z * av;
                    acc[3][r] += w4.w * av;
                }
            }
        }
    }

    float* pp = partial + (size_t)((ks * 4 + b) * 27) * HW;
#pragma unroll
    for (int u = 0; u < 4; ++u) {
        int oc = ocg * 4 + u;
        if (oc < 27) {
#pragma unroll
            for (int r = 0; r < 2; ++r)
                pp[(size_t)oc * HW + (y0 + r) * WW + x] = acc[u][r];
        }
    }
}

// ---------------- K4: reduce K-splits, add bias, sigmoid for mask ----------------
__global__ void finalize_kernel(const float* __restrict__ partial,
                                const float* __restrict__ ob, const float* __restrict__ mb,
                                float* __restrict__ offs, float* __restrict__ maskv) {
    int idx = blockIdx.x * blockDim.x + threadIdx.x; // 4*27*4096
    if (idx >= BB * 27 * HW) return;
    int p = idx & 4095;
    int j = (idx >> 12) % 27;
    int b = (idx >> 12) / 27;
    float s = 0.f;
#pragma unroll
    for (int ks = 0; ks < 4; ks++) s += partial[(size_t)((ks * 4 + b) * 27 + j) * HW + p];
    if (j < 18) {
        offs[(size_t)(b * 18 + j) * HW + p] = s + ob[j];
    } else {
        float m = s + mb[j - 18];
        maskv[(size_t)(b * 9 + (j - 18)) * HW + p] = 1.f / (1.f + expf(-m));
    }
}

// ---------------- K5: deformable conv gather + einsum ----------------
__global__ __launch_bounds__(256) void deform_kernel(
    const float* __restrict__ search, const float* __restrict__ offs,
    const float* __restrict__ maskv, const float* __restrict__ wt,
    const float* __restrict__ db, float* __restrict__ out) {
    int blk = blockIdx.x;  // b*128 + tile
    int b = blk >> 7, tile = blk & 127;
    int p0 = tile * 32;
    int tid = threadIdx.x;

    __shared__ int4 idxs[288];
    __shared__ float4 wgts[288];
    __shared__ float smp[CC * 32];

    for (int i = tid; i < 288; i += 256) {
        int k = i >> 5, t = i & 31;
        int p = p0 + t;
        int y = p >> 6, x = p & 63;
        float dy = offs[((size_t)(b * 18 + 2 * k)) * HW + p];
        float dx = offs[((size_t)(b * 18 + 2 * k + 1)) * HW + p];
        float m = maskv[((size_t)(b * 9 + k)) * HW + p];
        float py = (float)(y + k / 3 - 1) + dy;
        float px = (float)(x + k % 3 - 1) + dx;
        float fy0 = floorf(py), fx0 = floorf(px);
        float wy = py - fy0, wx = px - fx0;
        int y0 = (int)fy0, x0 = (int)fx0;
        bool vy0 = (y0 >= 0) && (y0 < HH);
        bool vy1 = (y0 + 1 >= 0) && (y0 + 1 < HH);
        bool vx0 = (x0 >= 0) && (x0 < WW);
        bool vx1 = (x0 + 1 >= 0) && (x0 + 1 < WW);
        float w00 = (vy0 && vx0) ? (1.f - wy) * (1.f - wx) * m : 0.f;
        float w01 = (vy0 && vx1) ? (1.f - wy) * wx * m : 0.f;
        float w10 = (vy1 && vx0) ? wy * (1.f - wx) * m : 0.f;
        float w11 = (vy1 && vx1) ? wy * wx * m : 0.f;
        int y0c = min(max(y0, 0), HH - 1), y1c = min(max(y0 + 1, 0), HH - 1);
        int x0c = min(max(x0, 0), WW - 1), x1c = min(max(x0 + 1, 0), WW - 1);
        idxs[i] = make_int4(y0c * WW + x0c, y0c * WW + x1c, y1c * WW + x0c, y1c * WW + x1c);
        wgts[i] = make_float4(w00, w01, w10, w11);
    }
    __syncthreads();

    float4 acc[4][2];
#pragma unroll
    for (int u = 0; u < 4; u++) {
        acc[u][0] = make_float4(0.f, 0.f, 0.f, 0.f);
        acc[u][1] = make_float4(0.f, 0.f, 0.f, 0.f);
    }

    int t_ = tid & 31, cg = tid >> 5;
    int o_lane = tid >> 2, tq = tid & 3;
    const float* sb = search + (size_t)b * CC * HW;

    for (int k = 0; k < 9; k++) {
        __syncthreads();
        int4 id = idxs[k * 32 + t_];
        float4 wg = wgts[k * 32 + t_];
#pragma unroll 4
        for (int j = 0; j < 32; j++) {
            int c = cg + 8 * j;
            const float* pl = sb + (size_t)c * HW;
            float v = wg.x * pl[id.x] + wg.y * pl[id.y] + wg.z * pl[id.z] + wg.w * pl[id.w];
            smp[c * 32 + t_] = v;
        }
        __syncthreads();

        const float* wk = wt + (size_t)k * CC * 256;
#pragma unroll 4
        for (int c = 0; c < CC; c++) {
            float4 s4a = *(const float4*)&smp[c * 32 + tq * 4];
            float4 s4b = *(const float4*)&smp[c * 32 + 16 + tq * 4];
            const float* wc = wk + c * 256;
#pragma unroll
            for (int u = 0; u < 4; u++) {
                float w_ = wc[u * 64 + o_lane];
                acc[u][0].x += w_ * s4a.x;
                acc[u][0].y += w_ * s4a.y;
                acc[u][0].z += w_ * s4a.z;
                acc[u][0].w += w_ * s4a.w;
                acc[u][1].x += w_ * s4b.x;
                acc[u][1].y += w_ * s4b.y;
                acc[u][1].z += w_ * s4b.z;
                acc[u][1].w += w_ * s4b.w;
            }
        }
    }

#pragma unroll
    for (int u = 0; u < 4; u++) {
        int o = u * 64 + o_lane;
        float bias = db[o];
        float* op = out + ((size_t)(b * CC + o)) * HW + p0 + tq * 4;
        float4 r0 = make_float4(acc[u][0].x + bias, acc[u][0].y + bias,
                                acc[u][0].z + bias, acc[u][0].w + bias);
        float4 r1 = make_float4(acc[u][1].x + bias, acc[u][1].y + bias,
                                acc[u][1].z + bias, acc[u][1].w + bias);
        *(float4*)(op) = r0;
        *(float4*)(op + 16) = r1;
    }
}

extern "C" void kernel_launch(void* const* d_in, const int* in_sizes, int n_in,
                              void* d_out, int out_size, void* d_ws, size_t ws_size,
                              hipStream_t stream) {
    const float* tmpl = (const float*)d_in[0];
    const float* search = (const float*)d_in[1];
    const float* ow = (const float*)d_in[2];
    const float* ob = (const float*)d_in[3];
    const float* mw = (const float*)d_in[4];
    const float* mb = (const float*)d_in[5];
    const float* dw = (const float*)d_in[6];
    const float* db = (const float*)d_in[7];
    float* out = (float*)d_out;

    float* ws = (float*)d_ws;
    float* offsv = ws;                      // 4*18*4096   = 294912
    float* maskv = offsv + 294912;          // 4*9*4096    = 147456
    float* wtb = maskv + 147456;            // 9*256*256   = 589824
    float* wt2 = wtb + 589824;              // 512*9*32    = 147456
    float* partial = wt2 + 147456;          // 4*4*27*4096 = 1769472
    // total ~11.8 MB

    transpose_w_kernel<<<(9 * CC * CC + 255) / 256, 256, 0, stream>>>(dw, wtb);
    build_wt2_kernel<<<(CCOMB * 9 * 32 + 255) / 256, 256, 0, stream>>>(ow, mw, wt2);
    offmask_gemm<<<512, 512, 0, stream>>>(tmpl, search, wt2, partial);
    finalize_kernel<<<(BB * 27 * HW + 255) / 256, 256, 0, stream>>>(partial, ob, mb, offsv, maskv);
    deform_kernel<<<BB * 128, 256, 0, stream>>>(search, offsv, maskv, wtb, db, out);
}

// Round 3
// 280.820 us; speedup vs baseline: 4.5250x; 1.5749x over previous
//
#include <hip/hip_runtime.h>
#include <math.h>

#define BB 4
#define CC 256
#define HT 32
#define WT 32
#define HH 64
#define WW 64
#define HW 4096
#define CCOMB 512

typedef __attribute__((ext_vector_type(8))) _Float16 half8;
typedef __attribute__((ext_vector_type(4))) _Float16 half4;
typedef __attribute__((ext_vector_type(4))) float f32x4;

__device__ inline void gld16(const void* g, void* l) {
    __builtin_amdgcn_global_load_lds((const __attribute__((address_space(1))) void*)g,
                                     (__attribute__((address_space(3))) void*)l, 16, 0, 0);
}

// ---------------- K1: build offset/mask weight matrix wt2[c][tap][32] ----------------
__global__ void build_wt2_kernel(const float* __restrict__ ow, const float* __restrict__ mw,
                                 float* __restrict__ wt2) {
    int idx = blockIdx.x * blockDim.x + threadIdx.x; // 512*9*32
    if (idx >= CCOMB * 9 * 32) return;
    int oc = idx & 31;
    int tap = (idx >> 5) % 9;
    int c = idx / 288;
    float v = 0.f;
    if (oc < 18) v = ow[(size_t)(oc * CCOMB + c) * 9 + tap];
    else if (oc < 27 && tap == 4) v = mw[(size_t)(oc - 18) * CCOMB + c];
    wt2[idx] = v;
}

// ---------------- K2: deform weights (o,c,k) -> f16 W3[o][k*256+c] ----------------
__global__ void w3_kernel(const float* __restrict__ dw, _Float16* __restrict__ W3) {
    int idx = blockIdx.x * blockDim.x + threadIdx.x; // 256*2304
    if (idx >= CC * 2304) return;
    int o = idx / 2304;
    int r = idx - o * 2304;
    int k = r >> 8, c = r & 255;
    W3[idx] = (_Float16)dw[(size_t)(o * CC + c) * 9 + k];
}

// ---------------- K3: offset+mask conv as register-tiled GEMM ----------------
__global__ __launch_bounds__(512) void offmask_gemm(
    const float* __restrict__ tmpl, const float* __restrict__ search,
    const float* __restrict__ wt2, float* __restrict__ partial) {
    int blk = blockIdx.x;
    int ks = blk >> 7;
    int b = (blk >> 5) & 3;
    int yt = blk & 31;
    int y0 = yt * 2;
    int tid = threadIdx.x;
    int ocg = tid >> 6;
    int x = tid & 63;

    __shared__ __align__(16) float act_s[16 * 4 * 68];
    __shared__ __align__(16) float wt_s[16 * 288];

    float acc[4][2];
#pragma unroll
    for (int u = 0; u < 4; u++) { acc[u][0] = 0.f; acc[u][1] = 0.f; }

    int c0g = ks * 128;
    const float* tp_b = tmpl + (size_t)b * CC * (HT * WT);
    const float* se_b = search + (size_t)b * CC * HW;

    for (int chunk = 0; chunk < 8; ++chunk) {
        int cbase = c0g + chunk * 16;
        __syncthreads();
        const float* wsrc = wt2 + (size_t)cbase * 288;
        for (int j = tid; j < 16 * 288; j += 512) wt_s[j] = wsrc[j];
        for (int j = tid; j < 4096; j += 512) {
            int cw = j >> 8;
            int row = (j >> 6) & 3;
            int xx = j & 63;
            int gy = y0 - 1 + row;
            float v = 0.f;
            if (gy >= 0 && gy < HH) {
                int cg = cbase + cw;
                if (cg < CC) {
                    const float* tp = tp_b + (size_t)cg * (HT * WT);
                    float sy = 0.5f * (float)gy - 0.25f;
                    float sx = 0.5f * (float)xx - 0.25f;
                    float fy0 = floorf(sy), fx0 = floorf(sx);
                    float wy = sy - fy0, wx = sx - fx0;
                    int yy0 = (int)fy0, xx0 = (int)fx0;
                    int y0c = min(max(yy0, 0), HT - 1), y1c = min(max(yy0 + 1, 0), HT - 1);
                    int x0c = min(max(xx0, 0), WT - 1), x1c = min(max(xx0 + 1, 0), WT - 1);
                    float v00 = tp[y0c * WT + x0c], v01 = tp[y0c * WT + x1c];
                    float v10 = tp[y1c * WT + x0c], v11 = tp[y1c * WT + x1c];
                    v = (1.f - wy) * ((1.f - wx) * v00 + wx * v01) +
                        wy * ((1.f - wx) * v10 + wx * v11);
                } else {
                    v = se_b[(size_t)(cg - CC) * HW + gy * WW + xx];
                }
            }
            act_s[cw * 272 + row * 68 + xx + 1] = v;
        }
        if (tid < 64) {
            int cw = tid >> 2, row = tid & 3;
            act_s[cw * 272 + row * 68 + 0] = 0.f;
            act_s[cw * 272 + row * 68 + 65] = 0.f;
        }
        __syncthreads();

#pragma unroll 2
        for (int cw = 0; cw < 16; ++cw) {
            float a[4][3];
#pragma unroll
            for (int row = 0; row < 4; ++row)
#pragma unroll
                for (int kx = 0; kx < 3; ++kx)
                    a[row][kx] = act_s[cw * 272 + row * 68 + x + kx];
            const float* wp = &wt_s[cw * 288 + ocg * 4];
#pragma unroll
            for (int t = 0; t < 9; ++t) {
                float4 w4 = *(const float4*)(wp + t * 32);
                int ky = t / 3, kx = t % 3;
#pragma unroll
                for (int r = 0; r < 2; ++r) {
                    float av = a[r + ky][kx];
                    acc[0][r] += w4.x * av;
                    acc[1][r] += w4.y * av;
                    acc[2][r] += w4.z * av;
                    acc[3][r] += w4.w * av;
                }
            }
        }
    }

    float* pp = partial + (size_t)((ks * 4 + b) * 27) * HW;
#pragma unroll
    for (int u = 0; u < 4; ++u) {
        int oc = ocg * 4 + u;
        if (oc < 27) {
#pragma unroll
            for (int r = 0; r < 2; ++r)
                pp[(size_t)oc * HW + (y0 + r) * WW + x] = acc[u][r];
        }
    }
}

// ---------------- K4: reduce K-splits, add bias, sigmoid for mask ----------------
__global__ void finalize_kernel(const float* __restrict__ partial,
                                const float* __restrict__ ob, const float* __restrict__ mb,
                                float* __restrict__ offs, float* __restrict__ maskv) {
    int idx = blockIdx.x * blockDim.x + threadIdx.x; // 4*27*4096
    if (idx >= BB * 27 * HW) return;
    int p = idx & 4095;
    int j = (idx >> 12) % 27;
    int b = (idx >> 12) / 27;
    float s = 0.f;
#pragma unroll
    for (int ks = 0; ks < 4; ks++) s += partial[(size_t)((ks * 4 + b) * 27 + j) * HW + p];
    if (j < 18) {
        offs[(size_t)(b * 18 + j) * HW + p] = s + ob[j];
    } else {
        float m = s + mb[j - 18];
        maskv[(size_t)(b * 9 + (j - 18)) * HW + p] = 1.f / (1.f + expf(-m));
    }
}

// ---------------- K5: bilinear gather -> f16 S_T[b][p][k*256+c] ----------------
// block = (b, 32-px tile), 256 threads = (cg 0..7, pl 0..31)
__global__ __launch_bounds__(256) void sample_kernel(
    const float* __restrict__ search, const float* __restrict__ offs,
    const float* __restrict__ maskv, _Float16* __restrict__ S_T) {
    int blk = blockIdx.x;  // b*128 + ptile
    int b = blk >> 7, ptile = blk & 127;
    int p0 = ptile * 32;
    int tid = threadIdx.x;

    __shared__ int4 idxs[288];
    __shared__ float4 wgts[288];
    __shared__ _Float16 ts[256 * 33];  // [c][pl] pad-33 rows (66B)

    for (int i = tid; i < 288; i += 256) {
        int k = i >> 5, t = i & 31;
        int p = p0 + t;
        int y = p >> 6, x = p & 63;
        float dy = offs[((size_t)(b * 18 + 2 * k)) * HW + p];
        float dx = offs[((size_t)(b * 18 + 2 * k + 1)) * HW + p];
        float m = maskv[((size_t)(b * 9 + k)) * HW + p];
        float py = (float)(y + k / 3 - 1) + dy;
        float px = (float)(x + k % 3 - 1) + dx;
        float fy0 = floorf(py), fx0 = floorf(px);
        float wy = py - fy0, wx = px - fx0;
        int y0 = (int)fy0, x0 = (int)fx0;
        bool vy0 = (y0 >= 0) && (y0 < HH);
        bool vy1 = (y0 + 1 >= 0) && (y0 + 1 < HH);
        bool vx0 = (x0 >= 0) && (x0 < WW);
        bool vx1 = (x0 + 1 >= 0) && (x0 + 1 < WW);
        float w00 = (vy0 && vx0) ? (1.f - wy) * (1.f - wx) * m : 0.f;
        float w01 = (vy0 && vx1) ? (1.f - wy) * wx * m : 0.f;
        float w10 = (vy1 && vx0) ? wy * (1.f - wx) * m : 0.f;
        float w11 = (vy1 && vx1) ? wy * wx * m : 0.f;
        int y0c = min(max(y0, 0), HH - 1), y1c = min(max(y0 + 1, 0), HH - 1);
        int x0c = min(max(x0, 0), WW - 1), x1c = min(max(x0 + 1, 0), WW - 1);
        idxs[i] = make_int4(y0c * WW + x0c, y0c * WW + x1c, y1c * WW + x0c, y1c * WW + x1c);
        wgts[i] = make_float4(w00, w01, w10, w11);
    }
    __syncthreads();

    int cg = tid >> 5, pl = tid & 31;
    const float* sb = search + (size_t)b * CC * HW;

    for (int k = 0; k < 9; ++k) {
        int4 id = idxs[k * 32 + pl];
        float4 wg = wgts[k * 32 + pl];
#pragma unroll 4
        for (int j = 0; j < 32; ++j) {
            int c = cg * 32 + j;
            const float* pln = sb + (size_t)c * HW;
            float v = wg.x * pln[id.x] + wg.y * pln[id.y] + wg.z * pln[id.z] + wg.w * pln[id.w];
            ts[c * 33 + pl] = (_Float16)v;
        }
        __syncthreads();
#pragma unroll
        for (int i = 0; i < 8; ++i) {
            int idx = tid + 256 * i;
            int p_ = idx >> 6;  // 0..31
            int cq = idx & 63;
            half4 pack;
            pack.x = ts[(cq * 4 + 0) * 33 + p_];
            pack.y = ts[(cq * 4 + 1) * 33 + p_];
            pack.z = ts[(cq * 4 + 2) * 33 + p_];
            pack.w = ts[(cq * 4 + 3) * 33 + p_];
            *(half4*)&S_T[((size_t)(b * HW + p0 + p_)) * 2304 + k * 256 + cq * 4] = pack;
        }
        __syncthreads();
    }
}

// ---------------- K6: f16 MFMA GEMM out[b][o][p] = W3[o][kc] * S_T[b][p][kc] ----------
// 128x128 tile, BK=32, 256 threads = 4 waves (2x2 of 64x64), m97 structure
__global__ __launch_bounds__(256) void deform_mfma(
    const _Float16* __restrict__ W3, const _Float16* __restrict__ S_T,
    const float* __restrict__ db, float* __restrict__ out) {
    int blk = blockIdx.x;  // b(4) x ot(2) x pt(32)
    int b = blk >> 6;
    int ot = (blk >> 5) & 1;
    int pt = blk & 31;
    int o0 = ot * 128, p0 = pt * 128;
    int tid = threadIdx.x;
    int wave = tid >> 6, lane = tid & 63;
    int wo = (wave & 1) * 64, wp = (wave >> 1) * 64;

    __shared__ __align__(16) _Float16 As[128 * 32];
    __shared__ __align__(16) _Float16 Bs[128 * 32];

    f32x4 acc[4][4];
#pragma unroll
    for (int i = 0; i < 4; ++i)
#pragma unroll
        for (int j = 0; j < 4; ++j) acc[i][j] = (f32x4){0.f, 0.f, 0.f, 0.f};

    int srow = tid >> 2;  // 0..63
    int scol = tid & 3;   // 16B chunk
    const _Float16* Ag = W3 + (size_t)(o0 + srow) * 2304 + scol * 8;
    const _Float16* Bg = S_T + ((size_t)(b * HW + p0 + srow)) * 2304 + scol * 8;
    char* AsB = (char*)As + wave * 1024;
    char* BsB = (char*)Bs + wave * 1024;

    int fr = lane & 15, fc = (lane >> 4) * 8;

    for (int ks = 0; ks < 72; ++ks) {
        __syncthreads();
        gld16(Ag, AsB);
        gld16(Ag + 64 * 2304, AsB + 4096);
        gld16(Bg, BsB);
        gld16(Bg + 64 * 2304, BsB + 4096);
        Ag += 32;
        Bg += 32;
        __syncthreads();

        half8 fa[4], fb[4];
#pragma unroll
        for (int f = 0; f < 4; ++f) {
            fa[f] = *(const half8*)&As[(wo + f * 16 + fr) * 32 + fc];
            fb[f] = *(const half8*)&Bs[(wp + f * 16 + fr) * 32 + fc];
        }
#pragma unroll
        for (int i = 0; i < 4; ++i)
#pragma unroll
            for (int j = 0; j < 4; ++j)
                acc[i][j] = __builtin_amdgcn_mfma_f32_16x16x32_f16(fa[i], fb[j], acc[i][j], 0, 0, 0);
    }

    int col = lane & 15, rbase = (lane >> 4) * 4;
#pragma unroll
    for (int i = 0; i < 4; ++i) {
        int o_ = o0 + wo + i * 16 + rbase;
#pragma unroll
        for (int j = 0; j < 4; ++j) {
            int p_ = p0 + wp + j * 16 + col;
#pragma unroll
            for (int r = 0; r < 4; ++r) {
                out[((size_t)(b * CC + o_ + r)) * HW + p_] = acc[i][j][r] + db[o_ + r];
            }
        }
    }
}

extern "C" void kernel_launch(void* const* d_in, const int* in_sizes, int n_in,
                              void* d_out, int out_size, void* d_ws, size_t ws_size,
                              hipStream_t stream) {
    const float* tmpl = (const float*)d_in[0];
    const float* search = (const float*)d_in[1];
    const float* ow = (const float*)d_in[2];
    const float* ob = (const float*)d_in[3];
    const float* mw = (const float*)d_in[4];
    const float* mb = (const float*)d_in[5];
    const float* dw = (const float*)d_in[6];
    const float* db = (const float*)d_in[7];
    float* out = (float*)d_out;

    float* ws = (float*)d_ws;
    float* offsv = ws;                        // 294912 f
    float* maskv = offsv + 294912;            // 147456 f
    float* wt2 = maskv + 147456;              // 147456 f
    float* partial = wt2 + 147456;            // 1769472 f
    _Float16* W3 = (_Float16*)(partial + 1769472);   // 589824 h (16B-aligned)
    _Float16* S_T = W3 + 589824;              // 37748736 h
    // total ~86.1 MB

    build_wt2_kernel<<<(CCOMB * 9 * 32 + 255) / 256, 256, 0, stream>>>(ow, mw, wt2);
    w3_kernel<<<(CC * 2304 + 255) / 256, 256, 0, stream>>>(dw, W3);
    offmask_gemm<<<512, 512, 0, stream>>>(tmpl, search, wt2, partial);
    finalize_kernel<<<(BB * 27 * HW + 255) / 256, 256, 0, stream>>>(partial, ob, mb, offsv, maskv);
    sample_kernel<<<BB * 128, 256, 0, stream>>>(search, offsv, maskv, S_T);
    deform_mfma<<<256, 256, 0, stream>>>(W3, S_T, db, out);
}

// Round 4
// 135.033 us; speedup vs baseline: 9.4103x; 2.0796x over previous
//
#include <hip/hip_runtime.h>
#include <math.h>

#define BB 4
#define CC 256
#define HH 64
#define WW 64
#define HW 4096
#define XTR 4240   // padded rows per batch: 72 + 4096 + 72
#define XPAD 72

typedef __attribute__((ext_vector_type(8))) _Float16 half8;
typedef __attribute__((ext_vector_type(4))) float f32x4;

__device__ inline void gld16(const void* g, void* l) {
    __builtin_amdgcn_global_load_lds((const __attribute__((address_space(1))) void*)g,
                                     (__attribute__((address_space(3))) void*)l, 16, 0, 0);
}

// ---------------- K0: zero the pad rows of X_Tp ----------------
__global__ void xt_pad_kernel(_Float16* __restrict__ XT) {
    int idx = blockIdx.x * blockDim.x + threadIdx.x;  // 4*144*64
    if (idx >= 4 * 144 * 64) return;
    int w = idx & 63;
    int r = (idx >> 6) % 144;
    int b = idx / 9216;
    int pr = (r < 72) ? r : (r + 4096);
    half8 z = {};
    *(half8*)&XT[((size_t)b * XTR + pr) * 512 + w * 8] = z;
}

// ---------------- K1: build X_Tp f16 [b][row][512c], chunk-swizzled ----------------
// c 0..255 = bilinear-upsampled template; c 256..511 = search. 16B chunk w within each
// 128B group stored at position w ^ (row&7)  (row&7 == x&7).
__global__ __launch_bounds__(256) void xt_kernel(const float* __restrict__ tmpl,
                                                 const float* __restrict__ search,
                                                 _Float16* __restrict__ XT) {
    int blk = blockIdx.x;  // b(4) x y(64) x ct(8)
    int ct = blk & 7, y = (blk >> 3) & 63, b = blk >> 9;
    int tid = threadIdx.x;
    __shared__ _Float16 ts[64 * 72];

    if (ct >= 4) {
        const float* sp = search + ((size_t)(b * CC + (ct - 4) * 64) * HW) + y * 64;
        for (int it = 0; it < 16; ++it) {
            int c_l = it * 4 + (tid >> 6);
            int x = tid & 63;
            ts[c_l * 72 + x] = (_Float16)sp[(size_t)c_l * HW + x];
        }
    } else {
        float sy = 0.5f * (float)y - 0.25f;
        float fy = floorf(sy);
        float wy = sy - fy;
        int y0 = (int)fy;
        int y0c = min(max(y0, 0), 31), y1c = min(max(y0 + 1, 0), 31);
        const float* tp0 = tmpl + ((size_t)(b * CC + ct * 64) * 1024);
        for (int it = 0; it < 16; ++it) {
            int c_l = it * 4 + (tid >> 6);
            int x = tid & 63;
            float sx = 0.5f * (float)x - 0.25f;
            float fx = floorf(sx);
            float wx = sx - fx;
            int x0 = (int)fx;
            int x0c = min(max(x0, 0), 31), x1c = min(max(x0 + 1, 0), 31);
            const float* tp = tp0 + (size_t)c_l * 1024;
            float v00 = tp[y0c * 32 + x0c], v01 = tp[y0c * 32 + x1c];
            float v10 = tp[y1c * 32 + x0c], v11 = tp[y1c * 32 + x1c];
            ts[c_l * 72 + x] = (_Float16)((1.f - wy) * ((1.f - wx) * v00 + wx * v01) +
                                          wy * ((1.f - wx) * v10 + wx * v11));
        }
    }
    __syncthreads();
    size_t rowbase = (size_t)b * XTR + XPAD + (size_t)y * 64;
    for (int it = 0; it < 2; ++it) {
        int idx = it * 256 + tid;
        int x = idx >> 3, w = idx & 7;
        half8 o;
#pragma unroll
        for (int j = 0; j < 8; ++j) o[j] = ts[(w * 8 + j) * 72 + x];
        *(half8*)&XT[(rowbase + x) * 512 + ct * 64 + ((w ^ (x & 7)) * 8)] = o;
    }
}

// ---------------- K2: offset/mask weights -> W2 f16 [chunk][tap][oc32][q^(oc&7)] ------
__global__ void w2_kernel(const float* __restrict__ ow, const float* __restrict__ mw,
                          _Float16* __restrict__ W2) {
    int idx = blockIdx.x * blockDim.x + threadIdx.x;  // 18432
    if (idx >= 18432) return;
    int q = idx & 7;
    int oc = (idx >> 3) & 31;
    int tap = (idx >> 8) % 9;
    int ch = idx / 2304;
    int c0 = ch * 64 + (q ^ (oc & 7)) * 8;
    half8 o;
#pragma unroll
    for (int j = 0; j < 8; ++j) {
        int c = c0 + j;
        float v = 0.f;
        if (oc < 18) v = ow[((size_t)oc * 512 + c) * 9 + tap];
        else if (oc < 27 && tap == 4) v = mw[(size_t)(oc - 18) * 512 + c];
        o[j] = (_Float16)v;
    }
    *(half8*)&W2[(size_t)idx * 8] = o;
}

// ---------------- K3: deform weights (o,c,k) -> f16 W3[o][k*256+c] (plain) -----------
__global__ void w3_kernel(const float* __restrict__ dw, _Float16* __restrict__ W3) {
    int idx = blockIdx.x * blockDim.x + threadIdx.x;  // 256*2304
    if (idx >= CC * 2304) return;
    int o = idx / 2304;
    int r = idx - o * 2304;
    int k = r >> 8, c = r & 255;
    W3[idx] = (_Float16)dw[(size_t)(o * CC + c) * 9 + k];
}

// ---------------- K4: offset+mask conv as MFMA GEMM over shifted X_Tp ----------------
// block = (b, 128-px tile). 256 thr = 4 waves, wave w -> pixels p0+w*32..+32.
__global__ __launch_bounds__(256) void offmask_mfma(
    const _Float16* __restrict__ XT, const _Float16* __restrict__ W2,
    const float* __restrict__ ob, const float* __restrict__ mb,
    float* __restrict__ offs, float* __restrict__ maskv) {
    int blk = blockIdx.x;
    int b = blk >> 5, pt = blk & 31;
    int p0 = pt * 128;
    int tid = threadIdx.x, wave = tid >> 6, lane = tid & 63;
    int l15 = lane & 15, kq = lane >> 4;

    __shared__ __align__(16) _Float16 A_s[18432];   // [tap 9][oc 32][64c] 36864 B
    __shared__ __align__(16) _Float16 B_s[16896];   // [264 rows][64c]     33792 B

    f32x4 acc[2][2];
#pragma unroll
    for (int m = 0; m < 2; ++m)
#pragma unroll
        for (int n = 0; n < 2; ++n) acc[m][n] = (f32x4){0.f, 0.f, 0.f, 0.f};

    const char* xrow = (const char*)(XT + ((size_t)b * XTR + XPAD + p0 - 65) * 512);
    half8 z8 = {};

    for (int ch = 0; ch < 8; ++ch) {
        __syncthreads();
        const char* srcA = (const char*)W2 + (size_t)ch * 36864;
#pragma unroll
        for (int it = 0; it < 9; ++it) {
            int b16 = it * 256 + wave * 64;
            gld16(srcA + (size_t)(b16 + lane) * 16, (char*)A_s + b16 * 16);
        }
#pragma unroll
        for (int it = 0; it < 9; ++it) {
            int b16 = it * 256 + wave * 64;
            if (b16 < 2112) {
                int c16 = b16 + lane;
                int r_u = c16 >> 3, q = c16 & 7;
                gld16(xrow + (size_t)r_u * 1024 + ch * 128 + q * 16, (char*)B_s + b16 * 16);
            }
        }
        __syncthreads();

#pragma unroll
        for (int tap = 0; tap < 9; ++tap) {
            int ky = tap / 3 - 1, kx = tap % 3 - 1;
            int dlt = ky * 64 + kx;
            int key = (l15 + dlt + 72) & 7;
            int x0_ = (wave * 32 + l15) & 63;
            int x1_ = (wave * 32 + 16 + l15) & 63;
            bool iv0 = (kx == -1 && x0_ == 0) || (kx == 1 && x0_ == 63);
            bool iv1 = (kx == -1 && x1_ == 0) || (kx == 1 && x1_ == 63);
            int r0 = wave * 32 + l15 + 65 + dlt;
#pragma unroll
            for (int ks = 0; ks < 2; ++ks) {
                int qa = ((ks * 4 + kq) ^ (l15 & 7)) * 8;
                int qb = ((ks * 4 + kq) ^ key) * 8;
                half8 fa0 = *(const half8*)&A_s[tap * 2048 + l15 * 64 + qa];
                half8 fa1 = *(const half8*)&A_s[tap * 2048 + (16 + l15) * 64 + qa];
                half8 fb0 = *(const half8*)&B_s[r0 * 64 + qb];
                half8 fb1 = *(const half8*)&B_s[(r0 + 16) * 64 + qb];
                if (iv0) fb0 = z8;
                if (iv1) fb1 = z8;
                acc[0][0] = __builtin_amdgcn_mfma_f32_16x16x32_f16(fa0, fb0, acc[0][0], 0, 0, 0);
                acc[1][0] = __builtin_amdgcn_mfma_f32_16x16x32_f16(fa1, fb0, acc[1][0], 0, 0, 0);
                acc[0][1] = __builtin_amdgcn_mfma_f32_16x16x32_f16(fa0, fb1, acc[0][1], 0, 0, 0);
                acc[1][1] = __builtin_amdgcn_mfma_f32_16x16x32_f16(fa1, fb1, acc[1][1], 0, 0, 0);
            }
        }
    }

#pragma unroll
    for (int m = 0; m < 2; ++m)
#pragma unroll
        for (int nf = 0; nf < 2; ++nf) {
            int px = p0 + wave * 32 + nf * 16 + l15;
#pragma unroll
            for (int r = 0; r < 4; ++r) {
                int oc = m * 16 + kq * 4 + r;
                float v = acc[m][nf][r];
                if (oc < 18) {
                    offs[(size_t)(b * 18 + oc) * HW + px] = v + ob[oc];
                } else if (oc < 27) {
                    float s = v + mb[oc - 18];
                    maskv[(size_t)(b * 9 + oc - 18) * HW + px] = 1.f / (1.f + expf(-s));
                }
            }
        }
}

// ---------------- K5: bilinear gather from X_Tp -> f16 S_T[b][p][k*256+c] ------------
// block = (b, 64-px tile). Lanes 0..31 = 8-channel octs of one (p,k) -> 512B stores.
__global__ __launch_bounds__(256) void sample_kernel(
    const _Float16* __restrict__ XT, const float* __restrict__ offs,
    const float* __restrict__ maskv, _Float16* __restrict__ S_T) {
    int blk = blockIdx.x;  // b*64 + pt
    int b = blk >> 6, pt = blk & 63;
    int p0 = pt * 64;
    int tid = threadIdx.x;

    __shared__ ushort4 r4[576];
    __shared__ float4 wg4[576];

    for (int i = tid; i < 576; i += 256) {
        int k = i >> 6, t = i & 63;
        int p = p0 + t;
        int y = p >> 6, x = p & 63;
        float dy = offs[((size_t)(b * 18 + 2 * k)) * HW + p];
        float dx = offs[((size_t)(b * 18 + 2 * k + 1)) * HW + p];
        float m = maskv[((size_t)(b * 9 + k)) * HW + p];
        float py = (float)(y + k / 3 - 1) + dy;
        float px = (float)(x + k % 3 - 1) + dx;
        float fy0 = floorf(py), fx0 = floorf(px);
        float wy = py - fy0, wx = px - fx0;
        int y0 = (int)fy0, x0 = (int)fx0;
        bool vy0 = (y0 >= 0) && (y0 < HH);
        bool vy1 = (y0 + 1 >= 0) && (y0 + 1 < HH);
        bool vx0 = (x0 >= 0) && (x0 < WW);
        bool vx1 = (x0 + 1 >= 0) && (x0 + 1 < WW);
        float w00 = (vy0 && vx0) ? (1.f - wy) * (1.f - wx) * m : 0.f;
        float w01 = (vy0 && vx1) ? (1.f - wy) * wx * m : 0.f;
        float w10 = (vy1 && vx0) ? wy * (1.f - wx) * m : 0.f;
        float w11 = (vy1 && vx1) ? wy * wx * m : 0.f;
        int y0c = min(max(y0, 0), HH - 1), y1c = min(max(y0 + 1, 0), HH - 1);
        int x0c = min(max(x0, 0), WW - 1), x1c = min(max(x0 + 1, 0), WW - 1);
        r4[i] = make_ushort4((ushort)(y0c * 64 + x0c), (ushort)(y0c * 64 + x1c),
                             (ushort)(y1c * 64 + x0c), (ushort)(y1c * 64 + x1c));
        wg4[i] = make_float4(w00, w01, w10, w11);
    }
    __syncthreads();

    const _Float16* xb = XT + ((size_t)b * XTR + XPAD) * 512;
    int oct = tid & 31;
    int gg64 = (4 + (oct >> 3)) * 64;  // search half: groups 4..7
    int w0 = oct & 7;

    for (int k = 0; k < 9; ++k) {
#pragma unroll 2
        for (int it = 0; it < 8; ++it) {
            int p_l = it * 8 + (tid >> 5);
            ushort4 rr = r4[k * 64 + p_l];
            float4 w = wg4[k * 64 + p_l];
            half8 c00 = *(const half8*)(xb + (size_t)rr.x * 512 + gg64 + ((w0 ^ (rr.x & 7)) * 8));
            half8 c01 = *(const half8*)(xb + (size_t)rr.y * 512 + gg64 + ((w0 ^ (rr.y & 7)) * 8));
            half8 c10 = *(const half8*)(xb + (size_t)rr.z * 512 + gg64 + ((w0 ^ (rr.z & 7)) * 8));
            half8 c11 = *(const half8*)(xb + (size_t)rr.w * 512 + gg64 + ((w0 ^ (rr.w & 7)) * 8));
            half8 o;
#pragma unroll
            for (int j = 0; j < 8; ++j) {
                float v = w.x * (float)c00[j] + w.y * (float)c01[j] +
                          w.z * (float)c10[j] + w.w * (float)c11[j];
                o[j] = (_Float16)v;
            }
            *(half8*)&S_T[((size_t)(b * HW + p0 + p_l)) * 2304 + k * 256 + oct * 8] = o;
        }
    }
}

// ---------------- K6: f16 MFMA GEMM out[b][o][p] = W3[o][kc] * S_T[b][p][kc] ----------
// 128x128 tile, BK=32, 4 waves; src-side chunk swizzle q^(row&3) on staging + reads.
__global__ __launch_bounds__(256) void deform_mfma(
    const _Float16* __restrict__ W3, const _Float16* __restrict__ S_T,
    const float* __restrict__ db, float* __restrict__ out) {
    int blk = blockIdx.x;  // b(4) x ot(2) x pt(32)
    int b = blk >> 6;
    int ot = (blk >> 5) & 1;
    int pt = blk & 31;
    int o0 = ot * 128, p0 = pt * 128;
    int tid = threadIdx.x;
    int wave = tid >> 6, lane = tid & 63;
    int wo = (wave & 1) * 64, wp = (wave >> 1) * 64;

    __shared__ __align__(16) _Float16 As[128 * 32];
    __shared__ __align__(16) _Float16 Bs[128 * 32];

    f32x4 acc[4][4];
#pragma unroll
    for (int i = 0; i < 4; ++i)
#pragma unroll
        for (int j = 0; j < 4; ++j) acc[i][j] = (f32x4){0.f, 0.f, 0.f, 0.f};

    int srow = tid >> 2;  // 0..63
    int scol = tid & 3;
    int ssw = (scol ^ (srow & 3)) * 8;  // source-side swizzle (16B chunks)
    const _Float16* Ag = W3 + (size_t)(o0 + srow) * 2304 + ssw;
    const _Float16* Bg = S_T + ((size_t)(b * HW + p0 + srow)) * 2304 + ssw;
    char* AsB = (char*)As + wave * 1024;
    char* BsB = (char*)Bs + wave * 1024;

    int fr = lane & 15, kq8 = lane >> 4;
    int fcs = (kq8 ^ (fr & 3)) * 8;  // swizzled chunk offset for frag reads

    for (int ks = 0; ks < 72; ++ks) {
        __syncthreads();
        gld16(Ag, AsB);
        gld16(Ag + 64 * 2304, AsB + 4096);
        gld16(Bg, BsB);
        gld16(Bg + 64 * 2304, BsB + 4096);
        Ag += 32;
        Bg += 32;
        __syncthreads();

        half8 fa[4], fb[4];
#pragma unroll
        for (int f = 0; f < 4; ++f) {
            fa[f] = *(const half8*)&As[(wo + f * 16 + fr) * 32 + fcs];
            fb[f] = *(const half8*)&Bs[(wp + f * 16 + fr) * 32 + fcs];
        }
#pragma unroll
        for (int i = 0; i < 4; ++i)
#pragma unroll
            for (int j = 0; j < 4; ++j)
                acc[i][j] = __builtin_amdgcn_mfma_f32_16x16x32_f16(fa[i], fb[j], acc[i][j], 0, 0, 0);
    }

    int col = lane & 15, rbase = (lane >> 4) * 4;
#pragma unroll
    for (int i = 0; i < 4; ++i) {
        int o_ = o0 + wo + i * 16 + rbase;
#pragma unroll
        for (int j = 0; j < 4; ++j) {
            int p_ = p0 + wp + j * 16 + col;
#pragma unroll
            for (int r = 0; r < 4; ++r) {
                out[((size_t)(b * CC + o_ + r)) * HW + p_] = acc[i][j][r] + db[o_ + r];
            }
        }
    }
}

extern "C" void kernel_launch(void* const* d_in, const int* in_sizes, int n_in,
                              void* d_out, int out_size, void* d_ws, size_t ws_size,
                              hipStream_t stream) {
    const float* tmpl = (const float*)d_in[0];
    const float* search = (const float*)d_in[1];
    const float* ow = (const float*)d_in[2];
    const float* ob = (const float*)d_in[3];
    const float* mw = (const float*)d_in[4];
    const float* mb = (const float*)d_in[5];
    const float* dw = (const float*)d_in[6];
    const float* db = (const float*)d_in[7];
    float* out = (float*)d_out;

    _Float16* XTp = (_Float16*)d_ws;                  // 4*4240*512   = 8,683,520 h
    _Float16* W2 = XTp + (size_t)4 * XTR * 512;       // 147,456 h
    _Float16* W3 = W2 + 147456;                       // 589,824 h
    _Float16* S_T = W3 + 589824;                      // 37,748,736 h
    float* offsv = (float*)(S_T + 37748736);          // 294,912 f
    float* maskv = offsv + 294912;                    // 147,456 f
    // total ~96.1 MB

    xt_pad_kernel<<<144, 256, 0, stream>>>(XTp);
    xt_kernel<<<2048, 256, 0, stream>>>(tmpl, search, XTp);
    w2_kernel<<<72, 256, 0, stream>>>(ow, mw, W2);
    w3_kernel<<<(CC * 2304 + 255) / 256, 256, 0, stream>>>(dw, W3);
    offmask_mfma<<<128, 256, 0, stream>>>(XTp, W2, ob, mb, offsv, maskv);
    sample_kernel<<<BB * 64, 256, 0, stream>>>(XTp, offsv, maskv, S_T);
    deform_mfma<<<256, 256, 0, stream>>>(W3, S_T, db, out);
}